// Round 7
// baseline (242.786 us; speedup 1.0000x reference)
//
#include <hip/hip_runtime.h>

// Reverb split:
//  k1: h2[c,y,x] = x[c,y,x] * Wsum[c,y,x]  -> d_ws   (pure streaming, no LDS/barrier)
//  k2: out[o,l]  = sum_c conv[c,o] * h2[c,l]         (LDS-tiled channel mix)
// Wsum[c,y,x] = sum_{i,j in 3x3, bounds} weight[c*9+i*3+j, (y+1-i)*256+(x+1-j)]

#define SS 256
#define CH 64
#define LL (SS * SS)

// ---------------- kernel 1: per-(c,y)-row streaming ----------------
__global__ __launch_bounds__(256, 4) void reverb_h2(
    const float* __restrict__ xin,   // (64, 256, 256)
    const float* __restrict__ w,     // (576, 65536)
    float* __restrict__ h2)          // (64, 65536) scratch
{
    const int t    = threadIdx.x;
    const int lane = t & 63;
    const int wv   = t >> 6;                     // 0..3
    const int task = (blockIdx.x << 2) + wv;     // 0..16383
    const int y    = task >> 6;                  // 0..255
    const int c    = task & 63;                  // 0..63
    const int px   = lane << 2;                  // 0..252

    const float4 xv = *reinterpret_cast<const float4*>(
        xin + (size_t)c * LL + (size_t)y * SS + px);

    float s0 = 0.f, s1 = 0.f, s2 = 0.f, s3 = 0.f;
    const float* wc = w + (size_t)c * 9 * LL;
#pragma unroll
    for (int i = 0; i < 3; ++i) {
        const int r = y + 1 - i;
        if ((unsigned)r < (unsigned)SS) {
            const float* base = wc + (size_t)(i * 3) * LL + (size_t)r * SS + px;
            const float4 v0 = *reinterpret_cast<const float4*>(base);          // j=0: col=p+1
            const float4 v1 = *reinterpret_cast<const float4*>(base + LL);     // j=1: col=p
            const float4 v2 = *reinterpret_cast<const float4*>(base + 2 * LL); // j=2: col=p-1
            s0 += v1.x; s1 += v1.y; s2 += v1.z; s3 += v1.w;
            float nx = __shfl_down(v0.x, 1);
            if (lane == 63) nx = 0.f;            // col 256: outside image
            s0 += v0.y; s1 += v0.z; s2 += v0.w; s3 += nx;
            float pv = __shfl_up(v2.w, 1);
            if (lane == 0) pv = 0.f;             // col -1: outside image
            s0 += pv; s1 += v2.x; s2 += v2.y; s3 += v2.z;
        }
    }
    float4 hr;
    hr.x = xv.x * s0; hr.y = xv.y * s1; hr.z = xv.z * s2; hr.w = xv.w * s3;
    *reinterpret_cast<float4*>(h2 + (size_t)c * LL + (size_t)y * SS + px) = hr;
}

// ---------------- kernel 2: channel mix, 128-px tiles ----------------
__global__ __launch_bounds__(256, 2) void reverb_mix(
    const float* __restrict__ h2,    // (64, 65536)
    const float* __restrict__ conv,  // (64, 64) [c][o]
    float* __restrict__ out)         // (64, 65536)
{
    __shared__ float hs[CH][128];    // 32 KB
    __shared__ float cv[CH][CH];     // 16 KB

    const int t   = threadIdx.x;
    const int px0 = blockIdx.x << 7; // 512 blocks * 128 px

    // stage conv: 1024 float4 / 256 threads
    {
        const float4* g4 = reinterpret_cast<const float4*>(conv);
        float4* s4 = reinterpret_cast<float4*>(&cv[0][0]);
#pragma unroll
        for (int k = 0; k < 4; ++k)
            s4[k * 256 + t] = g4[k * 256 + t];
    }
    // stage h2 tile: 2048 float4 / 256 threads = 8 each
    {
        float4* s4 = reinterpret_cast<float4*>(&hs[0][0]);
#pragma unroll
        for (int k = 0; k < 8; ++k) {
            const int f  = k * 256 + t;      // float4 index in tile
            const int r  = f >> 5;           // channel row
            const int c4 = f & 31;           // float4 col within 128-px row
            s4[f] = *reinterpret_cast<const float4*>(
                h2 + (size_t)r * LL + px0 + (c4 << 2));
        }
    }
    __syncthreads();

    // mix: q = px-quad (0..31), g = o-group (0..7, 8 o each)
    const int q  = t & 31;
    const int o0 = (t >> 5) << 3;

    float4 acc[8];
#pragma unroll
    for (int oo = 0; oo < 8; ++oo) acc[oo] = make_float4(0.f, 0.f, 0.f, 0.f);

#pragma unroll 8
    for (int c = 0; c < CH; ++c) {
        const float4 hv = *reinterpret_cast<const float4*>(&hs[c][q << 2]);
        const float4 ca = *reinterpret_cast<const float4*>(&cv[c][o0]);
        const float4 cb = *reinterpret_cast<const float4*>(&cv[c][o0 + 4]);
        const float cw[8] = {ca.x, ca.y, ca.z, ca.w, cb.x, cb.y, cb.z, cb.w};
#pragma unroll
        for (int oo = 0; oo < 8; ++oo) {
            acc[oo].x += cw[oo] * hv.x;
            acc[oo].y += cw[oo] * hv.y;
            acc[oo].z += cw[oo] * hv.z;
            acc[oo].w += cw[oo] * hv.w;
        }
    }

    float* op = out + px0 + (q << 2);
#pragma unroll
    for (int oo = 0; oo < 8; ++oo)
        *reinterpret_cast<float4*>(op + (size_t)(o0 + oo) * LL) = acc[oo];
}

// ---------------- fallback (round-6 fused) if ws too small ----------------
__global__ __launch_bounds__(1024, 4) void reverb_fused(
    const float* __restrict__ xin, const float* __restrict__ w,
    const float* __restrict__ conv, float* __restrict__ out)
{
    __shared__ float h2[CH][SS];
    __shared__ float cv[CH][CH];
    const int t = threadIdx.x, y = blockIdx.x, lane = t & 63, wv = t >> 6;
    reinterpret_cast<float4*>(&cv[0][0])[t] = reinterpret_cast<const float4*>(conv)[t];
    const int px = lane << 2;
#pragma unroll
    for (int cc = 0; cc < 4; ++cc) {
        const int c = (wv << 2) + cc;
        const float4 xv = *reinterpret_cast<const float4*>(xin + (size_t)c * LL + (size_t)y * SS + px);
        float s0 = 0.f, s1 = 0.f, s2 = 0.f, s3 = 0.f;
        const float* wc = w + (size_t)c * 9 * LL;
#pragma unroll
        for (int i = 0; i < 3; ++i) {
            const int r = y + 1 - i;
            if ((unsigned)r < (unsigned)SS) {
                const float* base = wc + (size_t)(i * 3) * LL + (size_t)r * SS + px;
                const float4 v0 = *reinterpret_cast<const float4*>(base);
                const float4 v1 = *reinterpret_cast<const float4*>(base + LL);
                const float4 v2 = *reinterpret_cast<const float4*>(base + 2 * LL);
                s0 += v1.x; s1 += v1.y; s2 += v1.z; s3 += v1.w;
                float nx = __shfl_down(v0.x, 1); if (lane == 63) nx = 0.f;
                s0 += v0.y; s1 += v0.z; s2 += v0.w; s3 += nx;
                float pv = __shfl_up(v2.w, 1);   if (lane == 0) pv = 0.f;
                s0 += pv; s1 += v2.x; s2 += v2.y; s3 += v2.z;
            }
        }
        float4 hr; hr.x = xv.x * s0; hr.y = xv.y * s1; hr.z = xv.z * s2; hr.w = xv.w * s3;
        *reinterpret_cast<float4*>(&h2[c][px]) = hr;
    }
    __syncthreads();
    const int p4 = (t & 63) << 2, o0 = (t >> 6) << 2;
    float4 acc[4];
#pragma unroll
    for (int oo = 0; oo < 4; ++oo) acc[oo] = make_float4(0.f, 0.f, 0.f, 0.f);
#pragma unroll 8
    for (int c = 0; c < CH; ++c) {
        const float4 hv = *reinterpret_cast<const float4*>(&h2[c][p4]);
        const float4 cw = *reinterpret_cast<const float4*>(&cv[c][o0]);
        acc[0].x += cw.x * hv.x; acc[0].y += cw.x * hv.y; acc[0].z += cw.x * hv.z; acc[0].w += cw.x * hv.w;
        acc[1].x += cw.y * hv.x; acc[1].y += cw.y * hv.y; acc[1].z += cw.y * hv.z; acc[1].w += cw.y * hv.w;
        acc[2].x += cw.z * hv.x; acc[2].y += cw.z * hv.y; acc[2].z += cw.z * hv.z; acc[2].w += cw.z * hv.w;
        acc[3].x += cw.w * hv.x; acc[3].y += cw.w * hv.y; acc[3].z += cw.w * hv.z; acc[3].w += cw.w * hv.w;
    }
    float* op = out + (size_t)o0 * LL + (size_t)y * SS + p4;
#pragma unroll
    for (int oo = 0; oo < 4; ++oo)
        *reinterpret_cast<float4*>(op + (size_t)oo * LL) = acc[oo];
}

extern "C" void kernel_launch(void* const* d_in, const int* in_sizes, int n_in,
                              void* d_out, int out_size, void* d_ws, size_t ws_size,
                              hipStream_t stream) {
    const float* x    = (const float*)d_in[0];  // (1,64,256,256)
    const float* w    = (const float*)d_in[1];  // (1,576,65536)
    const float* conv = (const float*)d_in[2];  // (64,64)
    float* out        = (float*)d_out;          // (1,64,256,256)

    const size_t h2_bytes = (size_t)CH * LL * sizeof(float);  // 16.78 MB
    if (ws_size >= h2_bytes) {
        float* h2 = (float*)d_ws;
        reverb_h2 <<<dim3(4096), dim3(256), 0, stream>>>(x, w, h2);
        reverb_mix<<<dim3(512),  dim3(256), 0, stream>>>(h2, conv, out);
    } else {
        reverb_fused<<<dim3(256), dim3(1024), 0, stream>>>(x, w, conv, out);
    }
}